// Round 13
// baseline (324.857 us; speedup 1.0000x reference)
//
#include <hip/hip_runtime.h>
#include <hip/hip_bf16.h>

#define B_   4
#define T_   16384
#define CH_  128
#define TCH_ 256
#define NL_  10
#define TT_  64
#define SHW_ 196          // 3-slab row stride in dwords (384 bf16 + 8 pad)
#define SWW_ 68           // window row stride in dwords (128 bf16 + 8 pad)

typedef __attribute__((ext_vector_type(8))) short short8;
typedef __attribute__((ext_vector_type(16))) float f32x16;

#define MFMA32(a, b, c) __builtin_amdgcn_mfma_f32_32x32x16_bf16(a, b, c, 0, 0, 0)

__device__ __forceinline__ unsigned short f2bf(float f) {
  unsigned u = __float_as_uint(f);
  return (unsigned short)((u + 0x7FFFu + ((u >> 16) & 1u)) >> 16);
}
// packed RNE f32x2 -> bf16x2 (low = lo, high = hi)
__device__ __forceinline__ unsigned pk2bf(float lo, float hi) {
  unsigned r;
  asm("v_cvt_pk_bf16_f32 %0, %1, %2" : "=v"(r) : "v"(lo), "v"(hi));
  return r;
}
__device__ __forceinline__ float bf2f(unsigned s) {
  return __uint_as_float((s & 0xFFFFu) << 16);
}
__device__ __forceinline__ float fast_tanh(float x) {
  float e = __expf(2.0f * fabsf(x));  // inf-safe: e=inf -> t=1
  float t = 1.0f - 2.0f / (e + 1.0f);
  return copysignf(t, x);
}
__device__ __forceinline__ float fast_sig(float x) {
  return 1.0f / (1.0f + __expf(-x));
}

// ---------------------------------------------------------------------------
// Prep: pack weights (bf16) into 32x32x16 MFMA A-fragment order (identical
// layout to round 9, verified).
// ---------------------------------------------------------------------------
__global__ __launch_bounds__(256) void pack_w(
    const float* __restrict__ conv_w, const float* __restrict__ w1x1,
    unsigned short* __restrict__ wpackA, unsigned short* __restrict__ wpack1) {
  const int NA = NL_ * 8 * 24 * 64 * 8;  // 983040
  int idx = blockIdx.x * 256 + threadIdx.x;
  if (idx < NA) {
    int j = idx & 7;
    int l = (idx >> 3) & 63;
    int t2 = idx >> 9;          // ks + 24*(of + 8*li)
    int ks = t2 % 24;
    int t3 = t2 / 24;
    int of = t3 & 7;
    int li = t3 >> 3;
    int o = 32 * of + (l & 31);
    int ck = 16 * ks + 8 * (l >> 5) + j;
    int c = ck & 127, ktap = ck >> 7;
    wpackA[idx] = f2bf(conv_w[((li * TCH_ + o) * CH_ + c) * 3 + ktap]);
  } else {
    int i2 = idx - NA;
    if (i2 < NL_ * 4 * 8 * 64 * 8) {
      int j = i2 & 7;
      int l = (i2 >> 3) & 63;
      int ks = (i2 >> 9) & 7;
      int of = (i2 >> 12) & 3;
      int li = i2 >> 14;
      int o = 32 * of + (l & 31);
      int c = 16 * ks + 8 * (l >> 5) + j;
      wpack1[i2] = f2bf(w1x1[(li * CH_ + o) * CH_ + c]);
    }
  }
}

// ---------------------------------------------------------------------------
// Fused init: blocks [0, 4096): rechannel h0 (bf16 [b][t][c]);
//             blocks [4096, 4352): out = b_head + w_head . head_init.
// ---------------------------------------------------------------------------
__global__ __launch_bounds__(256) void init_k(
    const float* __restrict__ x, const float* __restrict__ w_re,
    unsigned short* __restrict__ hb,
    const float* __restrict__ head_init, const float* __restrict__ w_head,
    const float* __restrict__ b_head, float* __restrict__ out) {
  if (blockIdx.x < 4096) {
    int flat = blockIdx.x * 256 + threadIdx.x;  // B*T*16 chunks of 8 ch
    int cid = flat & 15;
    int t = (flat >> 4) & (T_ - 1);
    int b = flat >> 18;
    float xv = x[b * T_ + t];
    const float* wr = w_re + cid * 8;
    union { short8 s; unsigned short u[8]; } o;
#pragma unroll
    for (int j = 0; j < 8; ++j) o.u[j] = f2bf(wr[j] * xv);
    *(short8*)(hb + (size_t)(b * T_ + t) * CH_ + cid * 8) = o.s;
  } else {
    int idx = (blockIdx.x - 4096) * 256 + threadIdx.x;  // over B*T
    int b = idx / T_;
    int t = idx - b * T_;
    float acc = b_head[0];
#pragma unroll 8
    for (int c = 0; c < CH_; ++c)
      acc += w_head[c] * head_init[(b * CH_ + c) * T_ + t];
    out[idx] = acc;
  }
}

// ---------------------------------------------------------------------------
// One fused layer, fully compile-time specialized on <D, FINAL>.
// 256 threads = 4 waves, t-tile 64, 32x32x16 MFMA, 3 blocks/CU.
// D<=32: union window [t0-2D, t0+64), (64+2D) rows, stride SWW_ (const).
// D>=64: 3-slab staging (stride SHW_), ctap = dwords 128..191.
// All strides, trip counts, and tap offsets are constants -> no runtime
// address multiplies, staging loop fully unrolled.
// ---------------------------------------------------------------------------
template <int D, bool FINAL>
__global__ __launch_bounds__(256, 3) void layer_k(
    const unsigned short* __restrict__ hin,  // bf16 [b][t][c]
    unsigned short* __restrict__ hob,        // bf16 [b][t][c] (layers 0..8)
    float* __restrict__ hof,                 // fp32 [b][c][t] (layer 9)
    const float* __restrict__ cin, float* __restrict__ out,
    const unsigned short* __restrict__ wA,   // conv A-frag pack (this layer)
    const unsigned short* __restrict__ w1p,  // 1x1 A-frag pack (this layer)
    const float* __restrict__ bconv,         // [256]
    const float* __restrict__ wmix,          // [256]
    const float* __restrict__ b1,            // [128]
    const float* __restrict__ w_head) {      // [128]
  constexpr bool smallD = (D <= 32);
  constexpr int strideW = smallD ? SWW_ : SHW_;
  constexpr int NROWS = smallD ? (TT_ + 2 * D) : TT_;

  __shared__ unsigned shW[NROWS * strideW];
  __shared__ float shR[4 * 64];         // [wave][t] head partials (1 KB)

  const int tid = threadIdx.x;
  const int b = blockIdx.y;
  // bijective XCD swizzle: 256 tiles per b, 8 XCDs, 32-tile chunks
  const int tile = (blockIdx.x & 7) * 32 + (blockIdx.x >> 3);
  const int t0 = tile * TT_;

  // ---- stage h (bf16, coalesced 16B chunks; compile-time trip count) ----
  if (smallD) {
    constexpr int NCHUNK = NROWS * 16;
#pragma unroll
    for (int it = 0; it < (NCHUNK + 255) / 256; ++it) {
      int flat = it * 256 + tid;
      if (NCHUNK % 256 == 0 || flat < NCHUNK) {
        int cid = flat & 15;
        int rw = flat >> 4;
        int t = t0 - 2 * D + rw;
        uint4 v = make_uint4(0u, 0u, 0u, 0u);
        if (t >= 0)
          v = *(const uint4*)(hin + ((size_t)(b * T_ + t) * CH_ + cid * 8));
        *(uint4*)(shW + rw * SWW_ + cid * 4) = v;
      }
    }
  } else {
#pragma unroll
    for (int it = 0; it < 12; ++it) {
      int flat = it * 256 + tid;
      int cid = flat & 15;
      int tt = (flat >> 4) & 63;
      int k = flat >> 10;            // 0..2
      int t = t0 + tt - (2 - k) * D;
      uint4 v = make_uint4(0u, 0u, 0u, 0u);
      if (t >= 0)
        v = *(const uint4*)(hin + ((size_t)(b * T_ + t) * CH_ + cid * 8));
      *(uint4*)(shW + tt * SHW_ + k * 64 + cid * 4) = v;
    }
  }
  __syncthreads();

  const int wave = __builtin_amdgcn_readfirstlane(tid >> 6);  // 0..3
  const int lane = tid & 63;
  const int ln = lane & 31;       // t within half-tile (C) / m,n (A,B)
  const int kg = lane >> 5;       // k-group (A,B) / o-offset +4 (C)

  // ---- conv GEMM: z[256x64] = W[256x384] * H[384x64], 24 K-steps ----
  f32x16 aL0, aL1, aH0, aH1;
#pragma unroll
  for (int i = 0; i < 16; ++i) { aL0[i] = 0.f; aL1[i] = 0.f; aH0[i] = 0.f; aH1[i] = 0.f; }

  const short8* wAv = (const short8*)wA;
#pragma unroll
  for (int ks = 0; ks < 24; ++ks) {
    short8 b0, b1f;
    if (smallD) {
      const int k = ks >> 3, cb = ks & 7;
      const int r0 = ln + k * D;     // k*D is a constant per unrolled ks
      b0 = *(const short8*)(shW + r0 * SWW_ + 8 * cb + 4 * kg);
      b1f = *(const short8*)(shW + (r0 + 32) * SWW_ + 8 * cb + 4 * kg);
    } else {
      b0 = *(const short8*)(shW + ln * SHW_ + 8 * ks + 4 * kg);
      b1f = *(const short8*)(shW + (32 + ln) * SHW_ + 8 * ks + 4 * kg);
    }
    short8 alo = wAv[(wave * 24 + ks) * 64 + lane];
    short8 ahi = wAv[((wave + 4) * 24 + ks) * 64 + lane];
    aL0 = MFMA32(alo, b0, aL0);
    aL1 = MFMA32(alo, b1f, aL1);
    aH0 = MFMA32(ahi, b0, aH0);
    aH1 = MFMA32(ahi, b1f, aH1);
  }
  __syncthreads();  // all conv reads done

  // ---- pre-read residual center tap into registers ----
  uint2 ct0[4], ct1[4];
#pragma unroll
  for (int r2 = 0; r2 < 4; ++r2) {
    const int dw = 16 * wave + 4 * r2 + 2 * kg;   // dword = c/2
    if (smallD) {
      ct0[r2] = *(const uint2*)(shW + (2 * D + ln) * SWW_ + dw);
      ct1[r2] = *(const uint2*)(shW + (2 * D + 32 + ln) * SWW_ + dw);
    } else {
      ct0[r2] = *(const uint2*)(shW + ln * SHW_ + 128 + dw);
      ct1[r2] = *(const uint2*)(shW + (32 + ln) * SHW_ + 128 + dw);
    }
  }
  __syncthreads();  // ctap reads done -> post may overwrite rows 0..63

  // ---- gating + head partials; post -> rows 0..63, dwords 0..63 ----
  const float cq0 = cin[b * T_ + t0 + ln];
  const float cq1 = cin[b * T_ + t0 + 32 + ln];
  float hs0 = 0.f, hs1 = 0.f;
#pragma unroll
  for (int r2 = 0; r2 < 4; ++r2) {
    const int o4 = 32 * wave + 8 * r2 + 4 * kg;
    const float4 bcL = *(const float4*)(bconv + o4);
    const float4 bcH = *(const float4*)(bconv + CH_ + o4);
    const float4 wmL = *(const float4*)(wmix + o4);
    const float4 wmH = *(const float4*)(wmix + CH_ + o4);
    const float4 wh = *(const float4*)(w_head + o4);
    float pv0[4], pv1[4];
#pragma unroll
    for (int j2 = 0; j2 < 4; ++j2) {
      const float bl = ((const float*)&bcL)[j2], bh = ((const float*)&bcH)[j2];
      const float ml = ((const float*)&wmL)[j2], mh = ((const float*)&wmH)[j2];
      const float w = ((const float*)&wh)[j2];
      float zl0 = aL0[4 * r2 + j2] + bl + ml * cq0;
      float zh0 = aH0[4 * r2 + j2] + bh + mh * cq0;
      pv0[j2] = fast_tanh(zl0) * fast_sig(zh0);
      hs0 += w * pv0[j2];
      float zl1 = aL1[4 * r2 + j2] + bl + ml * cq1;
      float zh1 = aH1[4 * r2 + j2] + bh + mh * cq1;
      pv1[j2] = fast_tanh(zl1) * fast_sig(zh1);
      hs1 += w * pv1[j2];
    }
    uint2 pk;
    const int dw = 16 * wave + 4 * r2 + 2 * kg;
    pk.x = pk2bf(pv0[0], pv0[1]);
    pk.y = pk2bf(pv0[2], pv0[3]);
    *(uint2*)(shW + ln * strideW + dw) = pk;
    pk.x = pk2bf(pv1[0], pv1[1]);
    pk.y = pk2bf(pv1[2], pv1[3]);
    *(uint2*)(shW + (32 + ln) * strideW + dw) = pk;
  }
  // head partial reduce across kg halves; lanes 0..31 hold t = ln (+32 tf)
  hs0 += __shfl_xor(hs0, 32);
  hs1 += __shfl_xor(hs1, 32);
  if (lane < 32) {
    shR[wave * 64 + ln] = hs0;
    shR[wave * 64 + 32 + ln] = hs1;
  }
  __syncthreads();  // post + shR ready

  // ---- 1x1 GEMM: delta[128x64] = W1 * post ----
  f32x16 d0, d1;
#pragma unroll
  for (int i = 0; i < 16; ++i) { d0[i] = 0.f; d1[i] = 0.f; }

  const short8* w1v = (const short8*)w1p;
#pragma unroll
  for (int ks = 0; ks < 8; ++ks) {
    short8 p0 = *(const short8*)(shW + ln * strideW + 8 * ks + 4 * kg);
    short8 p1 = *(const short8*)(shW + (32 + ln) * strideW + 8 * ks + 4 * kg);
    short8 a = w1v[(wave * 8 + ks) * 64 + lane];
    d0 = MFMA32(a, p0, d0);
    d1 = MFMA32(a, p1, d1);
  }

  // ---- head output (reads shR, written pre-barrier) ----
  if (tid < 64) {
    float tot = shR[tid] + shR[64 + tid] + shR[128 + tid] + shR[192 + tid];
    out[b * T_ + t0 + tid] += tot;
  }

  // ---- residual: res = ctap(regs) + b1 + delta ----
  float res0[16], res1[16];
#pragma unroll
  for (int r2 = 0; r2 < 4; ++r2) {
    const int o4 = 32 * wave + 8 * r2 + 4 * kg;
    const float4 b14 = *(const float4*)(b1 + o4);
    res0[4 * r2 + 0] = bf2f(ct0[r2].x) + ((const float*)&b14)[0] + d0[4 * r2 + 0];
    res0[4 * r2 + 1] = bf2f(ct0[r2].x >> 16) + ((const float*)&b14)[1] + d0[4 * r2 + 1];
    res0[4 * r2 + 2] = bf2f(ct0[r2].y) + ((const float*)&b14)[2] + d0[4 * r2 + 2];
    res0[4 * r2 + 3] = bf2f(ct0[r2].y >> 16) + ((const float*)&b14)[3] + d0[4 * r2 + 3];
    res1[4 * r2 + 0] = bf2f(ct1[r2].x) + ((const float*)&b14)[0] + d1[4 * r2 + 0];
    res1[4 * r2 + 1] = bf2f(ct1[r2].x >> 16) + ((const float*)&b14)[1] + d1[4 * r2 + 1];
    res1[4 * r2 + 2] = bf2f(ct1[r2].y) + ((const float*)&b14)[2] + d1[4 * r2 + 2];
    res1[4 * r2 + 3] = bf2f(ct1[r2].y >> 16) + ((const float*)&b14)[3] + d1[4 * r2 + 3];
  }

  if (!FINAL) {
    __syncthreads();  // all post reads done -> reuse rows 0..63
#pragma unroll
    for (int r2 = 0; r2 < 4; ++r2) {
      const int dw = 16 * wave + 4 * r2 + 2 * kg;
      uint2 pk;
      pk.x = pk2bf(res0[4 * r2 + 0], res0[4 * r2 + 1]);
      pk.y = pk2bf(res0[4 * r2 + 2], res0[4 * r2 + 3]);
      *(uint2*)(shW + ln * strideW + dw) = pk;
      pk.x = pk2bf(res1[4 * r2 + 0], res1[4 * r2 + 1]);
      pk.y = pk2bf(res1[4 * r2 + 2], res1[4 * r2 + 3]);
      *(uint2*)(shW + (32 + ln) * strideW + dw) = pk;
    }
    __syncthreads();
#pragma unroll
    for (int it = 0; it < 4; ++it) {
      int flat = it * 256 + tid;
      int cid = flat & 15;
      int tt = flat >> 4;
      *(uint4*)(hob + ((size_t)(b * T_ + t0 + tt) * CH_ + cid * 8)) =
          *(const uint4*)(shW + tt * strideW + cid * 4);
    }
  } else {
    // final layer: fp32 [b][c][t] into d_out
#pragma unroll
    for (int r2 = 0; r2 < 4; ++r2) {
#pragma unroll
      for (int j2 = 0; j2 < 4; ++j2) {
        const int o = 32 * wave + 8 * r2 + 4 * kg + j2;
        hof[(size_t)(b * CH_ + o) * T_ + t0 + ln] = res0[4 * r2 + j2];
        hof[(size_t)(b * CH_ + o) * T_ + t0 + 32 + ln] = res1[4 * r2 + j2];
      }
    }
  }
}

template <int D, bool FINAL>
static void launch_layer(const unsigned short* hin, unsigned short* hob,
                         float* hof, const float* c, float* out,
                         const unsigned short* wA, const unsigned short* w1p,
                         const float* bconv, const float* wmix,
                         const float* b1, const float* w_head,
                         hipStream_t stream) {
  layer_k<D, FINAL><<<dim3(T_ / TT_, B_), 256, 0, stream>>>(
      hin, hob, hof, c, out, wA, w1p, bconv, wmix, b1, w_head);
}

extern "C" void kernel_launch(void* const* d_in, const int* in_sizes, int n_in,
                              void* d_out, int out_size, void* d_ws, size_t ws_size,
                              hipStream_t stream) {
  const float* x         = (const float*)d_in[0];
  const float* c         = (const float*)d_in[1];
  const float* head_init = (const float*)d_in[2];
  const float* w_re      = (const float*)d_in[3];
  const float* conv_w    = (const float*)d_in[4];
  const float* conv_b    = (const float*)d_in[5];
  const float* mix_w     = (const float*)d_in[6];
  const float* w1x1      = (const float*)d_in[7];
  const float* b1x1      = (const float*)d_in[8];
  const float* w_head    = (const float*)d_in[9];
  const float* b_head    = (const float*)d_in[10];

  float* out = (float*)d_out;          // [B*T]
  float* hof = out + B_ * T_;          // fp32 h region of d_out

  unsigned short* hb0 = (unsigned short*)d_ws;          // bf16 h ping (16MB)
  unsigned short* hb1 = hb0 + (size_t)B_ * T_ * CH_;    // bf16 h pong (16MB)
  unsigned short* wpackA = hb1 + (size_t)B_ * T_ * CH_;
  unsigned short* wpack1 = wpackA + NL_ * 8 * 24 * 64 * 8;

  const int n_pack = NL_ * 8 * 24 * 64 * 8 + NL_ * 4 * 8 * 64 * 8;
  pack_w<<<(n_pack + 255) / 256, 256, 0, stream>>>(conv_w, w1x1, wpackA, wpack1);

  init_k<<<4096 + 256, 256, 0, stream>>>(x, w_re, hb0, head_init, w_head,
                                         b_head, out);

  typedef void (*LaunchFn)(const unsigned short*, unsigned short*, float*,
                           const float*, float*, const unsigned short*,
                           const unsigned short*, const float*, const float*,
                           const float*, const float*, hipStream_t);
  static const LaunchFn launchers[NL_] = {
      launch_layer<1, false>,   launch_layer<2, false>,
      launch_layer<4, false>,   launch_layer<8, false>,
      launch_layer<16, false>,  launch_layer<32, false>,
      launch_layer<64, false>,  launch_layer<128, false>,
      launch_layer<256, false>, launch_layer<512, true>};

  for (int li = 0; li < NL_; ++li) {
    const unsigned short* hin = (li & 1) ? hb1 : hb0;
    unsigned short* hob       = (li & 1) ? hb0 : hb1;
    launchers[li](hin, hob, hof, c, out,
                  wpackA + li * (8 * 24 * 64 * 8),
                  wpack1 + li * (4 * 8 * 64 * 8),
                  conv_b + li * TCH_,
                  mix_w + li * TCH_,
                  b1x1 + li * CH_,
                  w_head, stream);
  }
}

// Round 14
// 307.735 us; speedup vs baseline: 1.0556x; 1.0556x over previous
//
#include <hip/hip_runtime.h>
#include <hip/hip_bf16.h>

#define B_   4
#define T_   16384
#define CH_  128
#define TCH_ 256
#define NL_  10
#define TT_  64
#define SHW_ 196          // shH row stride in dwords (384 bf16 + 8 pad)

typedef __attribute__((ext_vector_type(8))) short short8;
typedef __attribute__((ext_vector_type(16))) float f32x16;

#define MFMA32(a, b, c) __builtin_amdgcn_mfma_f32_32x32x16_bf16(a, b, c, 0, 0, 0)

__device__ __forceinline__ unsigned short f2bf(float f) {
  unsigned u = __float_as_uint(f);
  return (unsigned short)((u + 0x7FFFu + ((u >> 16) & 1u)) >> 16);
}
// packed RNE f32x2 -> bf16x2 (low = lo, high = hi)
__device__ __forceinline__ unsigned pk2bf(float lo, float hi) {
  unsigned r;
  asm("v_cvt_pk_bf16_f32 %0, %1, %2" : "=v"(r) : "v"(lo), "v"(hi));
  return r;
}
__device__ __forceinline__ float bf2f(unsigned s) {
  return __uint_as_float((s & 0xFFFFu) << 16);
}
__device__ __forceinline__ float fast_tanh(float x) {
  float e = __expf(2.0f * fabsf(x));  // inf-safe: e=inf -> t=1
  float t = 1.0f - 2.0f / (e + 1.0f);
  return copysignf(t, x);
}
__device__ __forceinline__ float fast_sig(float x) {
  return 1.0f / (1.0f + __expf(-x));
}

// ---------------------------------------------------------------------------
// Fused prep (single dispatch, 3 independent block ranges):
//  [0, 4480):    pack weights (bf16) into 32x32x16 MFMA A-frag order (R9 layout)
//  [4480, 8576): rechannel h0 (bf16 [b][t][c])
//  [8576, 8832): out = b_head + w_head . head_init
// ---------------------------------------------------------------------------
__global__ __launch_bounds__(256) void prep_k(
    const float* __restrict__ conv_w, const float* __restrict__ w1x1,
    unsigned short* __restrict__ wpackA, unsigned short* __restrict__ wpack1,
    const float* __restrict__ x, const float* __restrict__ w_re,
    unsigned short* __restrict__ hb,
    const float* __restrict__ head_init, const float* __restrict__ w_head,
    const float* __restrict__ b_head, float* __restrict__ out) {
  const unsigned bid = blockIdx.x;
  if (bid < 4480u) {
    const int NA = NL_ * 8 * 24 * 64 * 8;  // 983040
    int idx = bid * 256 + threadIdx.x;
    if (idx < NA) {
      int j = idx & 7;
      int l = (idx >> 3) & 63;
      int t2 = idx >> 9;          // ks + 24*(of + 8*li)
      int ks = t2 % 24;
      int t3 = t2 / 24;
      int of = t3 & 7;
      int li = t3 >> 3;
      int o = 32 * of + (l & 31);
      int ck = 16 * ks + 8 * (l >> 5) + j;
      int c = ck & 127, ktap = ck >> 7;
      wpackA[idx] = f2bf(conv_w[((li * TCH_ + o) * CH_ + c) * 3 + ktap]);
    } else {
      int i2 = idx - NA;
      if (i2 < NL_ * 4 * 8 * 64 * 8) {
        int j = i2 & 7;
        int l = (i2 >> 3) & 63;
        int ks = (i2 >> 9) & 7;
        int of = (i2 >> 12) & 3;
        int li = i2 >> 14;
        int o = 32 * of + (l & 31);
        int c = 16 * ks + 8 * (l >> 5) + j;
        wpack1[i2] = f2bf(w1x1[(li * CH_ + o) * CH_ + c]);
      }
    }
  } else if (bid < 8576u) {
    int flat = (bid - 4480u) * 256 + threadIdx.x;  // B*T*16 chunks of 8 ch
    int cid = flat & 15;
    int t = (flat >> 4) & (T_ - 1);
    int b = flat >> 18;
    float xv = x[b * T_ + t];
    const float* wr = w_re + cid * 8;
    union { short8 s; unsigned short u[8]; } o;
#pragma unroll
    for (int j = 0; j < 8; ++j) o.u[j] = f2bf(wr[j] * xv);
    *(short8*)(hb + (size_t)(b * T_ + t) * CH_ + cid * 8) = o.s;
  } else {
    int idx = (bid - 8576u) * 256 + threadIdx.x;  // over B*T
    int b = idx / T_;
    int t = idx - b * T_;
    float acc = b_head[0];
#pragma unroll 8
    for (int c = 0; c < CH_; ++c)
      acc += w_head[c] * head_init[(b * CH_ + c) * T_ + t];
    out[idx] = acc;
  }
}

// ---------------------------------------------------------------------------
// One fused layer (exact R9 body — best verified, 310.8 us total).
// 256 threads = 4 waves, t-tile 64, 32x32x16 MFMA, 3 blocks/CU (LDS 51.2 KB).
// Wave w owns o-frags {w, w+4} (o-lo = 32w.., o-hi = o-lo+128) x both
// t-halves. C/D: t = 32tf + (lane&31), o = 32of + (reg&3)+8(reg>>2)+4(lane>>5).
// post aliases tap-0 slab of shH (dead after conv, barrier-protected).
// ---------------------------------------------------------------------------
__global__ __launch_bounds__(256, 3) void layer_k(
    const unsigned short* __restrict__ hin,  // bf16 [b][t][c]
    unsigned short* __restrict__ hob,        // bf16 [b][t][c] (layers 0..8)
    float* __restrict__ hof,                 // fp32 [b][c][t] (layer 9)
    const float* __restrict__ cin, float* __restrict__ out,
    const unsigned short* __restrict__ wA,   // conv A-frag pack (this layer)
    const unsigned short* __restrict__ w1p,  // 1x1 A-frag pack (this layer)
    const float* __restrict__ bconv,         // [256]
    const float* __restrict__ wmix,          // [256]
    const float* __restrict__ b1,            // [128]
    const float* __restrict__ w_head,        // [128]
    int d, int is_final) {
  __shared__ unsigned shH[TT_ * SHW_];  // [tt][k*128+c] bf16 (50176 B)
  __shared__ float shR[4 * 64];         // [wave][t] head partials (1 KB)

  const int tid = threadIdx.x;
  const int b = blockIdx.y;
  // bijective XCD swizzle: 256 tiles per b, 8 XCDs, 32-tile chunks
  const int tile = (blockIdx.x & 7) * 32 + (blockIdx.x >> 3);
  const int t0 = tile * TT_;

  // ---- stage H tiles (bf16, fully coalesced 16B chunks) ----
#pragma unroll
  for (int it = 0; it < 12; ++it) {
    int flat = it * 256 + tid;
    int cid = flat & 15;           // 16B chunk within tap row (8 channels)
    int tt = (flat >> 4) & 63;
    int k = flat >> 10;            // 0..2
    int t = t0 + tt - (2 - k) * d;
    uint4 v = make_uint4(0u, 0u, 0u, 0u);
    if (t >= 0)
      v = *(const uint4*)(hin + ((size_t)(b * T_ + t) * CH_ + cid * 8));
    *(uint4*)(shH + tt * SHW_ + k * 64 + cid * 4) = v;
  }
  __syncthreads();

  const int wave = __builtin_amdgcn_readfirstlane(tid >> 6);  // 0..3
  const int lane = tid & 63;
  const int ln = lane & 31;       // t within half-tile (C) / m,n (A,B)
  const int kg = lane >> 5;       // k-group (A,B) / o-offset +4 (C)

  // ---- conv GEMM: z[256x64] = W[256x384] * H[384x64], 24 K-steps ----
  f32x16 aL0, aL1, aH0, aH1;
#pragma unroll
  for (int i = 0; i < 16; ++i) { aL0[i] = 0.f; aL1[i] = 0.f; aH0[i] = 0.f; aH1[i] = 0.f; }

  const short8* wAv = (const short8*)wA;
#pragma unroll
  for (int ks = 0; ks < 24; ++ks) {
    short8 b0 = *(const short8*)(shH + ln * SHW_ + 8 * ks + 4 * kg);
    short8 b1f = *(const short8*)(shH + (32 + ln) * SHW_ + 8 * ks + 4 * kg);
    short8 alo = wAv[(wave * 24 + ks) * 64 + lane];
    short8 ahi = wAv[((wave + 4) * 24 + ks) * 64 + lane];
    aL0 = MFMA32(alo, b0, aL0);
    aL1 = MFMA32(alo, b1f, aL1);
    aH0 = MFMA32(ahi, b0, aH0);
    aH1 = MFMA32(ahi, b1f, aH1);
  }
  __syncthreads();  // tap-0 slab dead everywhere -> post may overwrite it

  // ---- gating + head partials; post -> tap-0 alias (dwords 0..63) ----
  const float cq0 = cin[b * T_ + t0 + ln];
  const float cq1 = cin[b * T_ + t0 + 32 + ln];
  float hs0 = 0.f, hs1 = 0.f;
#pragma unroll
  for (int r2 = 0; r2 < 4; ++r2) {
    const int o4 = 32 * wave + 8 * r2 + 4 * kg;
    const float4 bcL = *(const float4*)(bconv + o4);
    const float4 bcH = *(const float4*)(bconv + CH_ + o4);
    const float4 wmL = *(const float4*)(wmix + o4);
    const float4 wmH = *(const float4*)(wmix + CH_ + o4);
    const float4 wh = *(const float4*)(w_head + o4);
    float pv0[4], pv1[4];
#pragma unroll
    for (int j2 = 0; j2 < 4; ++j2) {
      const float bl = ((const float*)&bcL)[j2], bh = ((const float*)&bcH)[j2];
      const float ml = ((const float*)&wmL)[j2], mh = ((const float*)&wmH)[j2];
      const float w = ((const float*)&wh)[j2];
      float zl0 = aL0[4 * r2 + j2] + bl + ml * cq0;
      float zh0 = aH0[4 * r2 + j2] + bh + mh * cq0;
      pv0[j2] = fast_tanh(zl0) * fast_sig(zh0);
      hs0 += w * pv0[j2];
      float zl1 = aL1[4 * r2 + j2] + bl + ml * cq1;
      float zh1 = aH1[4 * r2 + j2] + bh + mh * cq1;
      pv1[j2] = fast_tanh(zl1) * fast_sig(zh1);
      hs1 += w * pv1[j2];
    }
    uint2 pk;
    const int dw = 16 * wave + 4 * r2 + 2 * kg;
    pk.x = pk2bf(pv0[0], pv0[1]);
    pk.y = pk2bf(pv0[2], pv0[3]);
    *(uint2*)(shH + ln * SHW_ + dw) = pk;
    pk.x = pk2bf(pv1[0], pv1[1]);
    pk.y = pk2bf(pv1[2], pv1[3]);
    *(uint2*)(shH + (32 + ln) * SHW_ + dw) = pk;
  }
  // head partial reduce across kg halves; lanes 0..31 hold t = ln (+32 tf)
  hs0 += __shfl_xor(hs0, 32);
  hs1 += __shfl_xor(hs1, 32);
  if (lane < 32) {
    shR[wave * 64 + ln] = hs0;
    shR[wave * 64 + 32 + ln] = hs1;
  }
  __syncthreads();  // post + shR ready

  // ---- 1x1 GEMM: delta[128x64] = W1 * post (from tap-0 alias) ----
  f32x16 d0, d1;
#pragma unroll
  for (int i = 0; i < 16; ++i) { d0[i] = 0.f; d1[i] = 0.f; }

  const short8* w1v = (const short8*)w1p;
#pragma unroll
  for (int ks = 0; ks < 8; ++ks) {
    short8 p0 = *(const short8*)(shH + ln * SHW_ + 8 * ks + 4 * kg);
    short8 p1 = *(const short8*)(shH + (32 + ln) * SHW_ + 8 * ks + 4 * kg);
    short8 a = w1v[(wave * 8 + ks) * 64 + lane];
    d0 = MFMA32(a, p0, d0);
    d1 = MFMA32(a, p1, d1);
  }

  // ---- head output (reads shR, written pre-barrier) ----
  if (tid < 64) {
    float tot = shR[tid] + shR[64 + tid] + shR[128 + tid] + shR[192 + tid];
    out[b * T_ + t0 + tid] += tot;
  }

  // ---- residual: res = hin(center tap, dw 128..191) + b1 + delta ----
  float res0[16], res1[16];
#pragma unroll
  for (int r2 = 0; r2 < 4; ++r2) {
    const int o4 = 32 * wave + 8 * r2 + 4 * kg;
    const float4 b14 = *(const float4*)(b1 + o4);
    const int dw = 16 * wave + 4 * r2 + 2 * kg;
    uint2 h0 = *(const uint2*)(shH + ln * SHW_ + 128 + dw);
    uint2 h1 = *(const uint2*)(shH + (32 + ln) * SHW_ + 128 + dw);
    res0[4 * r2 + 0] = bf2f(h0.x) + ((const float*)&b14)[0] + d0[4 * r2 + 0];
    res0[4 * r2 + 1] = bf2f(h0.x >> 16) + ((const float*)&b14)[1] + d0[4 * r2 + 1];
    res0[4 * r2 + 2] = bf2f(h0.y) + ((const float*)&b14)[2] + d0[4 * r2 + 2];
    res0[4 * r2 + 3] = bf2f(h0.y >> 16) + ((const float*)&b14)[3] + d0[4 * r2 + 3];
    res1[4 * r2 + 0] = bf2f(h1.x) + ((const float*)&b14)[0] + d1[4 * r2 + 0];
    res1[4 * r2 + 1] = bf2f(h1.x >> 16) + ((const float*)&b14)[1] + d1[4 * r2 + 1];
    res1[4 * r2 + 2] = bf2f(h1.y) + ((const float*)&b14)[2] + d1[4 * r2 + 2];
    res1[4 * r2 + 3] = bf2f(h1.y >> 16) + ((const float*)&b14)[3] + d1[4 * r2 + 3];
  }

  if (!is_final) {
    __syncthreads();  // all post/ctap reads done -> reuse dwords 0..63
#pragma unroll
    for (int r2 = 0; r2 < 4; ++r2) {
      const int dw = 16 * wave + 4 * r2 + 2 * kg;
      uint2 pk;
      pk.x = pk2bf(res0[4 * r2 + 0], res0[4 * r2 + 1]);
      pk.y = pk2bf(res0[4 * r2 + 2], res0[4 * r2 + 3]);
      *(uint2*)(shH + ln * SHW_ + dw) = pk;
      pk.x = pk2bf(res1[4 * r2 + 0], res1[4 * r2 + 1]);
      pk.y = pk2bf(res1[4 * r2 + 2], res1[4 * r2 + 3]);
      *(uint2*)(shH + (32 + ln) * SHW_ + dw) = pk;
    }
    __syncthreads();
#pragma unroll
    for (int it = 0; it < 4; ++it) {
      int flat = it * 256 + tid;
      int cid = flat & 15;
      int tt = flat >> 4;
      *(uint4*)(hob + ((size_t)(b * T_ + t0 + tt) * CH_ + cid * 8)) =
          *(const uint4*)(shH + tt * SHW_ + cid * 4);
    }
  } else {
    // final layer: fp32 [b][c][t] into d_out
#pragma unroll
    for (int r2 = 0; r2 < 4; ++r2) {
#pragma unroll
      for (int j2 = 0; j2 < 4; ++j2) {
        const int o = 32 * wave + 8 * r2 + 4 * kg + j2;
        hof[(size_t)(b * CH_ + o) * T_ + t0 + ln] = res0[4 * r2 + j2];
        hof[(size_t)(b * CH_ + o) * T_ + t0 + 32 + ln] = res1[4 * r2 + j2];
      }
    }
  }
}

extern "C" void kernel_launch(void* const* d_in, const int* in_sizes, int n_in,
                              void* d_out, int out_size, void* d_ws, size_t ws_size,
                              hipStream_t stream) {
  const float* x         = (const float*)d_in[0];
  const float* c         = (const float*)d_in[1];
  const float* head_init = (const float*)d_in[2];
  const float* w_re      = (const float*)d_in[3];
  const float* conv_w    = (const float*)d_in[4];
  const float* conv_b    = (const float*)d_in[5];
  const float* mix_w     = (const float*)d_in[6];
  const float* w1x1      = (const float*)d_in[7];
  const float* b1x1      = (const float*)d_in[8];
  const float* w_head    = (const float*)d_in[9];
  const float* b_head    = (const float*)d_in[10];

  float* out = (float*)d_out;          // [B*T]
  float* hof = out + B_ * T_;          // fp32 h region of d_out

  unsigned short* hb0 = (unsigned short*)d_ws;          // bf16 h ping (16MB)
  unsigned short* hb1 = hb0 + (size_t)B_ * T_ * CH_;    // bf16 h pong (16MB)
  unsigned short* wpackA = hb1 + (size_t)B_ * T_ * CH_;
  unsigned short* wpack1 = wpackA + NL_ * 8 * 24 * 64 * 8;

  // fused prep: 4480 pack blocks + 4096 rechannel blocks + 256 out_init
  prep_k<<<8832, 256, 0, stream>>>(conv_w, w1x1, wpackA, wpack1,
                                   x, w_re, hb0,
                                   head_init, w_head, b_head, out);

  const int dil[NL_] = {1, 2, 4, 8, 16, 32, 64, 128, 256, 512};
  for (int li = 0; li < NL_; ++li) {
    const unsigned short* hin = (li & 1) ? hb1 : hb0;
    unsigned short* hob       = (li & 1) ? hb0 : hb1;
    int is_final = (li == NL_ - 1);
    layer_k<<<dim3(T_ / TT_, B_), 256, 0, stream>>>(
        hin, hob, hof, c, out,
        wpackA + li * (8 * 24 * 64 * 8),
        wpack1 + li * (4 * 8 * 64 * 8),
        conv_b + li * TCH_,
        mix_w + li * TCH_,
        b1x1 + li * CH_,
        w_head,
        dil[li], is_final);
  }
}